// Round 1
// baseline (148.773 us; speedup 1.0000x reference)
//
#include <hip/hip_runtime.h>
#include <math.h>

// Shapes: B=4, X=128, T=256, PARAM_DIM=16, HIDDEN=128, EMB=128, DH=32, LATENT=32
// Outputs concatenated: u (4*256*128=131072), zt (4*256*1024=1048576), px (4*128*1024=524288)
//
// Workspace layout (floats):
//   ws[0    .. 511 ]  gx[b][j]  = ex @ px_We + px_be      (B x 128)
//   ws[512  .. 1023]  gt[b][j]  = et @ zt_We + zt_be      (B x 128)
//   ws[1024 .. 1055]  wcd[d]    = sum_j blk_Wc[d][j]*sw[j] (32)
//   ws[1056]          K (scalar)
//   ws[1088 .. ]      pxw_T[b][k][x] = px[b][x][k]*wcd[k>>5]/32   (B x 1024 x 128)

__global__ __launch_bounds__(128) void prep_kernel(
    const float* __restrict__ param,
    const float* __restrict__ p2e_W1, const float* __restrict__ p2e_b1,
    const float* __restrict__ p2e_W2, const float* __restrict__ p2e_b2,
    const float* __restrict__ e2ex_W, const float* __restrict__ e2ex_b,
    const float* __restrict__ e2et_W, const float* __restrict__ e2et_b,
    const float* __restrict__ px_We,  const float* __restrict__ px_be,
    const float* __restrict__ zt_We,  const float* __restrict__ zt_be,
    const float* __restrict__ h0,
    const float* __restrict__ blk_W1, const float* __restrict__ blk_b1,
    const float* __restrict__ blk_Wc, const float* __restrict__ blk_bc,
    const float* __restrict__ blk_W2, const float* __restrict__ blk_b2,
    const float* __restrict__ d_W,    const float* __restrict__ d_b,
    float* __restrict__ ws)
{
    const int j = threadIdx.x;           // 0..127
    __shared__ float sh0[128], sh1[128], sh2[128];

    if (blockIdx.x < 4) {
        const int b = blockIdx.x;
        // h1 = sin(param @ p2e_W1 + b1)
        float acc = p2e_b1[j];
        #pragma unroll
        for (int p = 0; p < 16; ++p) acc += param[b * 16 + p] * p2e_W1[p * 128 + j];
        sh0[j] = sinf(acc);
        __syncthreads();
        // e = h1 @ p2e_W2 + b2
        float e = p2e_b2[j];
        for (int k = 0; k < 128; ++k) e += sh0[k] * p2e_W2[k * 128 + j];
        sh1[j] = e;
        __syncthreads();
        // ex = e @ e2ex_W + b ; et = e @ e2et_W + b
        float ax = e2ex_b[j], at = e2et_b[j];
        for (int k = 0; k < 128; ++k) {
            float ek = sh1[k];
            ax += ek * e2ex_W[k * 128 + j];
            at += ek * e2et_W[k * 128 + j];
        }
        sh0[j] = ax; sh2[j] = at;
        __syncthreads();
        // gx = ex @ px_We + px_be ; gt = et @ zt_We + zt_be
        float gx = px_be[j], gt = zt_be[j];
        for (int k = 0; k < 128; ++k) {
            gx += sh0[k] * px_We[k * 128 + j];
            gt += sh2[k] * zt_We[k * 128 + j];
        }
        ws[b * 128 + j]       = gx;
        ws[512 + b * 128 + j] = gt;
    } else {
        // constants: s = sin(h0 @ blk_W1 + b1); w2d = blk_W2 @ d_W;
        // sw = s*w2d; wcd[d] = sum_j blk_Wc[d][j]*sw[j];
        // K = (h0+b2)@d_W + d_b + sw@bc
        float sacc = blk_b1[j];
        for (int k = 0; k < 128; ++k) sacc += h0[k] * blk_W1[k * 128 + j];
        float s = sinf(sacc);
        float w2d = 0.f;
        for (int m = 0; m < 128; ++m) w2d += blk_W2[j * 128 + m] * d_W[m];
        float sw = s * w2d;
        sh0[j] = sw;
        sh1[j] = (h0[j] + blk_b2[j]) * d_W[j] + sw * blk_bc[j];
        __syncthreads();
        if (j < 32) {
            float w = 0.f;
            for (int k = 0; k < 128; ++k) w += blk_Wc[j * 128 + k] * sh0[k];
            ws[1024 + j] = w;
        }
        for (int off = 64; off > 0; off >>= 1) {
            if (j < off) sh1[j] += sh1[j + off];
            __syncthreads();
        }
        if (j == 0) ws[1056] = sh1[0] + d_b[0];
    }
}

// px rows: 512 rows, 8 rows per block, col-chunks split 2 ways -> 128 blocks
__global__ __launch_bounds__(128) void px_kernel(
    const float* __restrict__ x,
    const float* __restrict__ Wx, const float* __restrict__ bx,
    const float* __restrict__ Wo, const float* __restrict__ bo,
    const float* __restrict__ mult_p,
    const float* __restrict__ ws,
    float* __restrict__ out_px, float* __restrict__ pxwT)
{
    const int j  = threadIdx.x;
    const int rt = blockIdx.x >> 1;         // row tile 0..63
    const int i0 = (blockIdx.x & 1) * 4;    // col-chunk start
    const int r0 = rt * 8;
    const int b  = r0 >> 7;
    const int xi0 = r0 & 127;

    __shared__ float f[8][128];
    const float wxj = Wx[j], bxj = bx[j];
    const float g = ws[b * 128 + j];
    #pragma unroll
    for (int rr = 0; rr < 8; ++rr)
        f[rr][j] = sinf(x[r0 + rr] * wxj + bxj) * g;
    __syncthreads();

    const float mult = mult_p[0];
    for (int i = i0; i < i0 + 4; ++i) {
        const int col = i * 128 + j;
        float acc[8];
        const float bias = bo[col];
        #pragma unroll
        for (int rr = 0; rr < 8; ++rr) acc[rr] = bias;
        for (int k = 0; k < 128; ++k) {
            const float w = Wo[k * 1024 + col];
            #pragma unroll
            for (int rr = 0; rr < 8; ++rr) acc[rr] += f[rr][k] * w;
        }
        const float scale = ws[1024 + (col >> 5)] * (1.0f / 32.0f);
        #pragma unroll
        for (int rr = 0; rr < 8; ++rr) {
            const float v = mult * acc[rr];
            out_px[(r0 + rr) * 1024 + col] = v;
            if (pxwT) pxwT[(b * 1024 + col) * 128 + xi0 + rr] = v * scale;
        }
    }
}

// zt rows: 1024 rows, 8 per block, col-split 2 -> 256 blocks
__global__ __launch_bounds__(128) void zt_kernel(
    const float* __restrict__ t,
    const float* __restrict__ Wx, const float* __restrict__ bx,
    const float* __restrict__ Wo, const float* __restrict__ bo,
    const float* __restrict__ mult_p,
    const float* __restrict__ ws,
    float* __restrict__ out_zt)
{
    const int j  = threadIdx.x;
    const int rt = blockIdx.x >> 1;
    const int i0 = (blockIdx.x & 1) * 4;
    const int r0 = rt * 8;
    const int b  = r0 >> 8;

    __shared__ float f[8][128];
    const float wxj = Wx[j], bxj = bx[j];
    const float g = ws[512 + b * 128 + j];
    #pragma unroll
    for (int rr = 0; rr < 8; ++rr)
        f[rr][j] = sinf(t[r0 + rr] * wxj + bxj) * g;
    __syncthreads();

    const float mult = mult_p[0];
    for (int i = i0; i < i0 + 4; ++i) {
        const int col = i * 128 + j;
        float acc[8];
        const float bias = bo[col];
        #pragma unroll
        for (int rr = 0; rr < 8; ++rr) acc[rr] = bias;
        for (int k = 0; k < 128; ++k) {
            const float w = Wo[k * 1024 + col];
            #pragma unroll
            for (int rr = 0; rr < 8; ++rr) acc[rr] += f[rr][k] * w;
        }
        #pragma unroll
        for (int rr = 0; rr < 8; ++rr)
            out_zt[(r0 + rr) * 1024 + col] = mult * acc[rr];
    }
}

// u contraction: u[b,t,x] = K + sum_k zt[b,t,k] * pxw_T[b,k,x]
// 1024 (b,t) rows, 4 per block -> 256 blocks; thread j = x.
__global__ __launch_bounds__(128) void u_kernel(
    const float* __restrict__ zt, const float* __restrict__ pxwT,
    const float* __restrict__ ws, float* __restrict__ out_u)
{
    const int j  = threadIdx.x;
    const int r0 = blockIdx.x * 4;          // b*256 + t
    const int b  = r0 >> 8;

    __shared__ float zrow[4][1024];
    #pragma unroll
    for (int rr = 0; rr < 4; ++rr)
        for (int i = 0; i < 8; ++i)
            zrow[rr][i * 128 + j] = zt[(r0 + rr) * 1024 + i * 128 + j];
    __syncthreads();

    const float K = ws[1056];
    float acc[4];
    #pragma unroll
    for (int rr = 0; rr < 4; ++rr) acc[rr] = K;

    const float* pw = pxwT + b * 1024 * 128 + j;
    for (int k = 0; k < 1024; ++k) {
        const float w = pw[k * 128];
        #pragma unroll
        for (int rr = 0; rr < 4; ++rr) acc[rr] += zrow[rr][k] * w;
    }
    #pragma unroll
    for (int rr = 0; rr < 4; ++rr)
        out_u[(r0 + rr) * 128 + j] = acc[rr];
}

// Fallback if workspace too small for pxw_T: read px straight from d_out.
__global__ __launch_bounds__(128) void u_naive_kernel(
    const float* __restrict__ zt, const float* __restrict__ px,
    const float* __restrict__ ws, float* __restrict__ out_u)
{
    const int r = blockIdx.x;               // b*256 + t
    const int b = r >> 8;
    const int j = threadIdx.x;
    __shared__ float zrow[1024];
    __shared__ float wc[32];
    for (int i = 0; i < 8; ++i) zrow[i * 128 + j] = zt[r * 1024 + i * 128 + j];
    if (j < 32) wc[j] = ws[1024 + j] * (1.0f / 32.0f);
    __syncthreads();
    const float* prow = px + (b * 128 + j) * 1024;
    float acc = ws[1056];
    for (int k = 0; k < 1024; ++k) acc += zrow[k] * prow[k] * wc[k >> 5];
    out_u[r * 128 + j] = acc;
}

extern "C" void kernel_launch(void* const* d_in, const int* in_sizes, int n_in,
                              void* d_out, int out_size, void* d_ws, size_t ws_size,
                              hipStream_t stream) {
    const float* x       = (const float*)d_in[0];
    const float* t       = (const float*)d_in[1];
    const float* param   = (const float*)d_in[2];
    const float* p2e_W1  = (const float*)d_in[3];
    const float* p2e_b1  = (const float*)d_in[4];
    const float* p2e_W2  = (const float*)d_in[5];
    const float* p2e_b2  = (const float*)d_in[6];
    const float* e2ex_W  = (const float*)d_in[7];
    const float* e2ex_b  = (const float*)d_in[8];
    const float* e2et_W  = (const float*)d_in[9];
    const float* e2et_b  = (const float*)d_in[10];
    const float* px_Wx   = (const float*)d_in[11];
    const float* px_bx   = (const float*)d_in[12];
    const float* px_We   = (const float*)d_in[13];
    const float* px_be   = (const float*)d_in[14];
    const float* px_Wo   = (const float*)d_in[15];
    const float* px_bo   = (const float*)d_in[16];
    const float* px_mult = (const float*)d_in[17];
    const float* zt_Wx   = (const float*)d_in[18];
    const float* zt_bx   = (const float*)d_in[19];
    const float* zt_We   = (const float*)d_in[20];
    const float* zt_be   = (const float*)d_in[21];
    const float* zt_Wo   = (const float*)d_in[22];
    const float* zt_bo   = (const float*)d_in[23];
    const float* zt_mult = (const float*)d_in[24];
    const float* h0      = (const float*)d_in[25];
    const float* blk_W1  = (const float*)d_in[26];
    const float* blk_b1  = (const float*)d_in[27];
    const float* blk_Wc  = (const float*)d_in[28];
    const float* blk_bc  = (const float*)d_in[29];
    const float* blk_W2  = (const float*)d_in[30];
    const float* blk_b2  = (const float*)d_in[31];
    const float* d_W     = (const float*)d_in[32];
    const float* d_bias  = (const float*)d_in[33];

    float* out    = (float*)d_out;
    float* out_u  = out;                       // 131072
    float* out_zt = out + 131072;              // 1048576
    float* out_px = out + 131072 + 1048576;    // 524288

    float* ws   = (float*)d_ws;
    float* pxwT = ws + 1088;
    const bool use_pw =
        ws_size >= (size_t)(1088 + 4 * 1024 * 128) * sizeof(float);

    prep_kernel<<<5, 128, 0, stream>>>(
        param, p2e_W1, p2e_b1, p2e_W2, p2e_b2,
        e2ex_W, e2ex_b, e2et_W, e2et_b,
        px_We, px_be, zt_We, zt_be,
        h0, blk_W1, blk_b1, blk_Wc, blk_bc, blk_W2, blk_b2,
        d_W, d_bias, ws);

    px_kernel<<<128, 128, 0, stream>>>(
        x, px_Wx, px_bx, px_Wo, px_bo, px_mult, ws,
        out_px, use_pw ? pxwT : nullptr);

    zt_kernel<<<256, 128, 0, stream>>>(
        t, zt_Wx, zt_bx, zt_Wo, zt_bo, zt_mult, ws, out_zt);

    if (use_pw)
        u_kernel<<<256, 128, 0, stream>>>(out_zt, pxwT, ws, out_u);
    else
        u_naive_kernel<<<1024, 128, 0, stream>>>(out_zt, out_px, ws, out_u);
}

// Round 2
// 61.236 us; speedup vs baseline: 2.4295x; 2.4295x over previous
//
#include <hip/hip_runtime.h>
#include <math.h>

// B=4, X=128, T=256, HIDDEN=128, EMB=128, DH=32, LATENT=32, K=DH*LATENT=1024
// Outputs: u (131072), zt (1048576), px (524288), concatenated in d_out.
//
// Algebraic collapse of the BlockMod tail (verified round 1, absmax 3.9e-3):
//   u[b,t,x] = K0 + sum_k zt[b,t,k] * px[b,x,k] * wcd[k>>5] / 32
//   with s = sin(h0@blk_W1+blk_b1); w2d = blk_W2@d_W; sw = s*w2d;
//   wcd[d] = blk_Wc[d,:]@sw;  K0 = (h0+blk_b2)@d_W + d_b + sw@blk_bc.
//
// 2 kernels, no workspace:
//   feat_kernel: 192 blocks (64 px-blocks of 8 rows, 128 zt-blocks of 8 rows).
//                Each block redundantly computes its per-batch g-vector
//                (4-stage GEMV chain, tiny), then 8x1024 GEMM vs Wo.
//   u_kernel:    128 blocks; per-batch GEMM zt_b @ px_b^T with LDS K-tiles.

__global__ __launch_bounds__(256) void feat_kernel(
    const float* __restrict__ x, const float* __restrict__ t,
    const float* __restrict__ param,
    const float* __restrict__ p2e_W1, const float* __restrict__ p2e_b1,
    const float* __restrict__ p2e_W2, const float* __restrict__ p2e_b2,
    const float* __restrict__ e2ex_W, const float* __restrict__ e2ex_b,
    const float* __restrict__ e2et_W, const float* __restrict__ e2et_b,
    const float* __restrict__ px_Wx, const float* __restrict__ px_bx,
    const float* __restrict__ px_We, const float* __restrict__ px_be,
    const float* __restrict__ px_Wo, const float* __restrict__ px_bo,
    const float* __restrict__ px_mult,
    const float* __restrict__ zt_Wx, const float* __restrict__ zt_bx,
    const float* __restrict__ zt_We, const float* __restrict__ zt_be,
    const float* __restrict__ zt_Wo, const float* __restrict__ zt_bo,
    const float* __restrict__ zt_mult,
    float* __restrict__ out_px, float* __restrict__ out_zt)
{
    const int tid = threadIdx.x;
    const bool is_zt = (blockIdx.x >= 64);
    const int r0 = (is_zt ? (blockIdx.x - 64) : blockIdx.x) * 8;
    const int b  = is_zt ? (r0 >> 8) : (r0 >> 7);

    const float* Wh = is_zt ? e2et_W : e2ex_W;
    const float* bh = is_zt ? e2et_b : e2ex_b;
    const float* We = is_zt ? zt_We : px_We;
    const float* be = is_zt ? zt_be : px_be;
    const float* Wx = is_zt ? zt_Wx : px_Wx;
    const float* bx = is_zt ? zt_bx : px_bx;
    const float* Wo = is_zt ? zt_Wo : px_Wo;
    const float* bo = is_zt ? zt_bo : px_bo;
    const float* coord = is_zt ? t : x;
    const float  mult  = is_zt ? zt_mult[0] : px_mult[0];
    float* outp = is_zt ? out_zt : out_px;

    __shared__ float shA[128], shB[128];
    __shared__ float f[8][128];

    // redundant per-block prep chain (threads 0..127): g = embedding head
    if (tid < 128) {
        float a = p2e_b1[tid];
        #pragma unroll
        for (int p = 0; p < 16; ++p) a += param[b * 16 + p] * p2e_W1[p * 128 + tid];
        shA[tid] = sinf(a);
    }
    __syncthreads();
    if (tid < 128) {
        float e = p2e_b2[tid];
        for (int k = 0; k < 128; ++k) e += shA[k] * p2e_W2[k * 128 + tid];
        shB[tid] = e;
    }
    __syncthreads();
    if (tid < 128) {
        float c = bh[tid];
        for (int k = 0; k < 128; ++k) c += shB[k] * Wh[k * 128 + tid];
        shA[tid] = c;
    }
    __syncthreads();
    if (tid < 128) {
        float g = be[tid];
        for (int k = 0; k < 128; ++k) g += shA[k] * We[k * 128 + tid];
        // f rows for this block's 8 coords
        const float wxj = Wx[tid], bxj = bx[tid];
        #pragma unroll
        for (int rr = 0; rr < 8; ++rr)
            f[rr][tid] = sinf(coord[r0 + rr] * wxj + bxj) * g;
    }
    __syncthreads();

    // GEMM: 8 rows x 1024 cols; thread owns 4 consecutive cols (float4)
    const int c0 = tid * 4;
    const float4 bias = *(const float4*)&bo[c0];
    float4 acc[8];
    #pragma unroll
    for (int rr = 0; rr < 8; ++rr) acc[rr] = bias;

    for (int k = 0; k < 128; ++k) {
        const float4 w = *(const float4*)&Wo[k * 1024 + c0];
        #pragma unroll
        for (int rr = 0; rr < 8; ++rr) {
            const float fv = f[rr][k];
            acc[rr].x += fv * w.x;
            acc[rr].y += fv * w.y;
            acc[rr].z += fv * w.z;
            acc[rr].w += fv * w.w;
        }
    }
    #pragma unroll
    for (int rr = 0; rr < 8; ++rr) {
        float4 v;
        v.x = mult * acc[rr].x; v.y = mult * acc[rr].y;
        v.z = mult * acc[rr].z; v.w = mult * acc[rr].w;
        *(float4*)&outp[(r0 + rr) * 1024 + c0] = v;
    }
}

// u[b,t,x] = K0 + sum_k zt[b,t,k] * (px[b,x,k] * wcd[k>>5]/32)
// Block: (b, 16 t-rows, 64 x-cols); 256 threads, 2x2 register tile.
// Grid: 4 b * 16 t-tiles * 2 x-halves = 128 blocks.
__global__ __launch_bounds__(256) void u_kernel(
    const float* __restrict__ zt, const float* __restrict__ px,
    const float* __restrict__ h0,
    const float* __restrict__ blk_W1, const float* __restrict__ blk_b1,
    const float* __restrict__ blk_Wc, const float* __restrict__ blk_bc,
    const float* __restrict__ blk_W2, const float* __restrict__ blk_b2,
    const float* __restrict__ d_W,    const float* __restrict__ d_b,
    float* __restrict__ out_u)
{
    const int tid = threadIdx.x;
    const int blk = blockIdx.x;
    const int b     = blk >> 5;
    const int rem   = blk & 31;
    const int t0    = (rem >> 1) * 16;
    const int x0    = (rem & 1) * 64;

    __shared__ float sw_sh[128];
    __shared__ float red[128];
    __shared__ float wcd[32];
    __shared__ float Kc;
    __shared__ float zts[16][68];   // row stride 272B = 17*16B (f4-aligned)
    __shared__ float pxs[64][68];

    // redundant constants: sw, wcd, K0
    if (tid < 128) {
        float sa = blk_b1[tid];
        for (int k = 0; k < 128; ++k) sa += h0[k] * blk_W1[k * 128 + tid];
        const float s = sinf(sa);
        float w2d = 0.f;
        for (int m = 0; m < 128; ++m) w2d += blk_W2[tid * 128 + m] * d_W[m];
        const float sw = s * w2d;
        sw_sh[tid] = sw;
        red[tid] = (h0[tid] + blk_b2[tid]) * d_W[tid] + sw * blk_bc[tid];
    }
    __syncthreads();
    if (tid < 32) {
        float w = 0.f;
        for (int k = 0; k < 128; ++k) w += blk_Wc[tid * 128 + k] * sw_sh[k];
        wcd[tid] = w * (1.0f / 32.0f);
    }
    if (tid < 64) red[tid] += red[tid + 64];
    __syncthreads();
    if (tid == 0) {
        float Ks = d_b[0];
        for (int i = 0; i < 64; ++i) Ks += red[i];
        Kc = Ks;
    }
    __syncthreads();

    const int tx = tid & 31;    // x = x0 + tx + 32*xr
    const int ty = tid >> 5;    // t = t0 + ty + 8*tr
    float a00 = 0.f, a01 = 0.f, a10 = 0.f, a11 = 0.f;

    const float* ztb = zt + (b * 256 + t0) * 1024;
    const float* pxb = px + (b * 128 + x0) * 1024;

    for (int kc = 0; kc < 1024; kc += 64) {
        // fill zts (16x64), scaled by wcd: 256 float4, one per thread
        {
            const int tt = tid >> 4;
            const int kk = (tid & 15) * 4;
            float4 v = *(const float4*)&ztb[tt * 1024 + kc + kk];
            const float s = wcd[(kc + kk) >> 5];
            v.x *= s; v.y *= s; v.z *= s; v.w *= s;
            *(float4*)&zts[tt][kk] = v;
        }
        // fill pxs (64x64): 1024 float4, four per thread
        #pragma unroll
        for (int i = 0; i < 4; ++i) {
            const int m  = tid + 256 * i;
            const int xx = m >> 4;
            const int kk = (m & 15) * 4;
            *(float4*)&pxs[xx][kk] = *(const float4*)&pxb[xx * 1024 + kc + kk];
        }
        __syncthreads();

        #pragma unroll
        for (int kk = 0; kk < 64; kk += 4) {
            const float4 z0 = *(const float4*)&zts[ty][kk];
            const float4 z1 = *(const float4*)&zts[ty + 8][kk];
            const float4 p0 = *(const float4*)&pxs[tx][kk];
            const float4 p1 = *(const float4*)&pxs[tx + 32][kk];
            a00 += z0.x * p0.x + z0.y * p0.y + z0.z * p0.z + z0.w * p0.w;
            a01 += z0.x * p1.x + z0.y * p1.y + z0.z * p1.z + z0.w * p1.w;
            a10 += z1.x * p0.x + z1.y * p0.y + z1.z * p0.z + z1.w * p0.w;
            a11 += z1.x * p1.x + z1.y * p1.y + z1.z * p1.z + z1.w * p1.w;
        }
        __syncthreads();
    }

    const float K0 = Kc;
    out_u[(b * 256 + t0 + ty)     * 128 + x0 + tx]      = K0 + a00;
    out_u[(b * 256 + t0 + ty)     * 128 + x0 + tx + 32] = K0 + a01;
    out_u[(b * 256 + t0 + ty + 8) * 128 + x0 + tx]      = K0 + a10;
    out_u[(b * 256 + t0 + ty + 8) * 128 + x0 + tx + 32] = K0 + a11;
}

extern "C" void kernel_launch(void* const* d_in, const int* in_sizes, int n_in,
                              void* d_out, int out_size, void* d_ws, size_t ws_size,
                              hipStream_t stream) {
    const float* x       = (const float*)d_in[0];
    const float* t       = (const float*)d_in[1];
    const float* param   = (const float*)d_in[2];
    const float* p2e_W1  = (const float*)d_in[3];
    const float* p2e_b1  = (const float*)d_in[4];
    const float* p2e_W2  = (const float*)d_in[5];
    const float* p2e_b2  = (const float*)d_in[6];
    const float* e2ex_W  = (const float*)d_in[7];
    const float* e2ex_b  = (const float*)d_in[8];
    const float* e2et_W  = (const float*)d_in[9];
    const float* e2et_b  = (const float*)d_in[10];
    const float* px_Wx   = (const float*)d_in[11];
    const float* px_bx   = (const float*)d_in[12];
    const float* px_We   = (const float*)d_in[13];
    const float* px_be   = (const float*)d_in[14];
    const float* px_Wo   = (const float*)d_in[15];
    const float* px_bo   = (const float*)d_in[16];
    const float* px_mult = (const float*)d_in[17];
    const float* zt_Wx   = (const float*)d_in[18];
    const float* zt_bx   = (const float*)d_in[19];
    const float* zt_We   = (const float*)d_in[20];
    const float* zt_be   = (const float*)d_in[21];
    const float* zt_Wo   = (const float*)d_in[22];
    const float* zt_bo   = (const float*)d_in[23];
    const float* zt_mult = (const float*)d_in[24];
    const float* h0      = (const float*)d_in[25];
    const float* blk_W1  = (const float*)d_in[26];
    const float* blk_b1  = (const float*)d_in[27];
    const float* blk_Wc  = (const float*)d_in[28];
    const float* blk_bc  = (const float*)d_in[29];
    const float* blk_W2  = (const float*)d_in[30];
    const float* blk_b2  = (const float*)d_in[31];
    const float* d_W     = (const float*)d_in[32];
    const float* d_bias  = (const float*)d_in[33];

    float* out    = (float*)d_out;
    float* out_u  = out;                       // 131072
    float* out_zt = out + 131072;              // 1048576
    float* out_px = out + 131072 + 1048576;    // 524288

    feat_kernel<<<192, 256, 0, stream>>>(
        x, t, param,
        p2e_W1, p2e_b1, p2e_W2, p2e_b2,
        e2ex_W, e2ex_b, e2et_W, e2et_b,
        px_Wx, px_bx, px_We, px_be, px_Wo, px_bo, px_mult,
        zt_Wx, zt_bx, zt_We, zt_be, zt_Wo, zt_bo, zt_mult,
        out_px, out_zt);

    u_kernel<<<128, 256, 0, stream>>>(
        out_zt, out_px, h0,
        blk_W1, blk_b1, blk_Wc, blk_bc, blk_W2, blk_b2,
        d_W, d_bias, out_u);
}